// Round 11
// baseline (44.427 us; speedup 1.0000x reference)
//
#include <hip/hip_runtime.h>
#include <math.h>

#define NN   1024
#define DD   256
#define NCLS 10

#define TI 64      // i rows per block
#define TJ 64      // j cols per block
#define DC 32      // d chunk per block (8 quads/row)
#define DSPLIT 8
#define NBLK ((NN / TI) * (NN / TJ) * DSPLIT)   // 16*16*8 = 2048

typedef float f32x4 __attribute__((ext_vector_type(4)));

// counts -> reciprocal weight tables (float), so pair_kernel never divides
__global__ __launch_bounds__(256) void count_kernel(const long long* __restrict__ tgt,
                                                    float* __restrict__ wtab) {
    __shared__ int c[NCLS];
    int tid = threadIdx.x;
    if (tid < NCLS) c[tid] = 0;
    __syncthreads();
    for (int k = tid; k < NN; k += 256) atomicAdd(&c[(int)tgt[k]], 1);
    __syncthreads();
    if (tid < NCLS) {
        wtab[tid]      = 1.0f / (float)c[tid];         // w_eq = 1/cnt
        wtab[16 + tid] = 1.0f / (float)(NN - c[tid]);  // w_ne = 1/(N-cnt)
    }
}

// Placement (both sides): row r, logical d-quad q -> physical quad (q + (r>>2)) & 7.
//  - j-read (row tx*4+rj, quad k): phys = (k + tx) & 7 -> 16 tx over 8 quads, 2-way (free).
//  - i-read (row ty*4+ri, quad k): phys = (k + ty) & 7 -> 4 ty/wave -> 4 quads, broadcast,
//    conflict-free.
//  - staging writes: uniform 8 accesses/bank = the b128 floor.
__global__ __launch_bounds__(256) void pair_kernel(
    const float* __restrict__ fm_s, const float* __restrict__ fm_t,
    const float* __restrict__ lv, const long long* __restrict__ tgt,
    const float* __restrict__ wtab, float* __restrict__ partials)
{
    __shared__ float Al[TI * DC];   // 8 KB : fs^2*iv + 0.5*lv
    __shared__ float Bl[TI * DC];   // 8 KB : -2*fs*iv
    __shared__ float Vl[TI * DC];   // 8 KB : iv
    __shared__ float Fl[TJ * DC];   // 8 KB : fm_t      => 32768 B -> 5 blocks/CU

    const int bid  = blockIdx.x;
    const int tile = bid >> 3;        // 0..255
    const int kd   = bid & 7;         // d-eighth
    const int i0   = (tile >> 4) * TI;
    const int j0   = (tile & 15) * TJ;
    const int doff = kd * DC;

    const int tid  = threadIdx.x;
    const int tx   = tid & 15;        // j-group: 4 cols
    const int ty   = tid >> 4;        // i-group: 4 rows
    const int lane = tid & 63;
    const int w    = tid >> 6;

    const int* tgt32 = (const int*)tgt;   // int64 low words, values 0..9

    // ---- staging: thread t owns (r, q) = (t>>3, t&7), rows r and r+32 ----
    const int sr = tid >> 3;          // 0..31
    const int sq = tid & 7;           // source d-quad
#pragma unroll
    for (int p = 0; p < 2; ++p) {
        const int r    = sr + p * 32;
        const int phys = (sq + (r >> 2)) & 7;
        // teacher
        f32x4 v = *(const f32x4*)&fm_t[(j0 + r) * DD + doff + sq * 4];
        *(f32x4*)&Fl[r * DC + phys * 4] = v;
        // student
        const int g = (i0 + r) * DD + doff + sq * 4;
        f32x4 fs = *(const f32x4*)&fm_s[g];
        f32x4 l  = *(const f32x4*)&lv[g];
        f32x4 A, B, V;
#pragma unroll
        for (int e = 0; e < 4; ++e) {
            const float iv = 0.5f * __expf(-l[e]);   // 1/(2e^l+1e-12), rel ~2e-6
            const float fsiv = fs[e] * iv;
            A[e] = fmaf(fsiv, fs[e], 0.5f * l[e]);
            B[e] = -2.0f * fsiv;
            V[e] = iv;
        }
        const int o = r * DC + phys * 4;
        *(f32x4*)&Al[o] = A;
        *(f32x4*)&Bl[o] = B;
        *(f32x4*)&Vl[o] = V;
    }

    __syncthreads();

    // 32 scalar accumulators -- small enough to stay fully VGPR-resident
    float s1[4][4], s2[4][4];
#pragma unroll
    for (int a = 0; a < 4; ++a)
#pragma unroll
        for (int b = 0; b < 4; ++b) { s1[a][b] = 0.f; s2[a][b] = 0.f; }

    // ---- main loop: 8 steps, logical d-quad k each ----
#pragma unroll 2
    for (int k = 0; k < 8; ++k) {
        // j-side: 4 rows (tx*4+rj), phys quad (k+tx)&7
        const f32x4* pf = (const f32x4*)&Fl[tx * 128 + ((k + tx) & 7) * 4];
        f32x4 f[4];
#pragma unroll
        for (int rj = 0; rj < 4; ++rj) f[rj] = pf[rj * 8];

        // i-side: 4 rows (ty*4+ri), phys quad (k+ty)&7
        const int iq = ((k + ty) & 7) * 4;
        const f32x4* pa = (const f32x4*)&Al[ty * 128 + iq];
        const f32x4* pb = (const f32x4*)&Bl[ty * 128 + iq];
        const f32x4* pv = (const f32x4*)&Vl[ty * 128 + iq];
#pragma unroll
        for (int ri = 0; ri < 4; ++ri) {
            const f32x4 fa = pa[ri * 8];
            const f32x4 fb = pb[ri * 8];
            const f32x4 fv = pv[ri * 8];
#pragma unroll
            for (int rj = 0; rj < 4; ++rj) {
#pragma unroll
                for (int e = 0; e < 4; ++e) {
                    const float fe = f[rj][e];
                    const float u  = fmaf(fv[e], fe, fb[e]);   // V*f + B
                    const float t  = fmaf(u, fe, fa[e]);       // (V*f+B)*f + A
                    s1[ri][rj] += t;
                    s2[ri][rj] += fabsf(t);                    // abs = VOP3 modifier
                }
            }
        }
    }

    // ---- epilogue: masked row-normalized weighting ----
    float csum = 0.f;
#pragma unroll
    for (int ri = 0; ri < 4; ++ri) {
        const int t    = tgt32[(i0 + ty * 4 + ri) * 2];
        const float wp = wtab[t];
        const float wn = wtab[16 + t];
#pragma unroll
        for (int rj = 0; rj < 4; ++rj) {
            const int tj = tgt32[(j0 + tx * 4 + rj) * 2];
            const float lp = 0.5f * (s2[ri][rj] + s1[ri][rj]);
            const float ln = 0.5f * (s2[ri][rj] - s1[ri][rj]);
            csum += (t == tj) ? lp * wp : ln * wn;
        }
    }

#pragma unroll
    for (int off = 32; off > 0; off >>= 1) csum += __shfl_down(csum, off);
    __syncthreads();
    if (lane == 0) Al[w] = csum;
    __syncthreads();
    if (tid == 0) partials[bid] = (Al[0] + Al[1]) + (Al[2] + Al[3]);
}

__global__ __launch_bounds__(256) void finalize_kernel(const float* __restrict__ partials,
                                                       float* __restrict__ out) {
    __shared__ float red[256];
    const int tid = threadIdx.x;
    float s = 0.f;
#pragma unroll
    for (int k = 0; k < NBLK / 256; ++k) s += partials[tid + k * 256];
    red[tid] = s;
    __syncthreads();
    for (int st = 128; st > 0; st >>= 1) {
        if (tid < st) red[tid] += red[tid + st];
        __syncthreads();
    }
    if (tid == 0) out[0] = red[0] * (1.0f / (float)NN);
}

extern "C" void kernel_launch(void* const* d_in, const int* in_sizes, int n_in,
                              void* d_out, int out_size, void* d_ws, size_t ws_size,
                              hipStream_t stream) {
    const float* fm_s    = (const float*)d_in[0];
    const float* fm_t    = (const float*)d_in[1];
    const float* lv      = (const float*)d_in[2];
    const long long* tgt = (const long long*)d_in[3];
    // fusion_true (d_in[4]) == 0 path implemented

    float* wtab     = (float*)d_ws;                 // 32 floats
    float* partials = (float*)((char*)d_ws + 256);  // NBLK floats

    hipLaunchKernelGGL(count_kernel, dim3(1), dim3(256), 0, stream, tgt, wtab);
    hipLaunchKernelGGL(pair_kernel, dim3(NBLK), dim3(256), 0, stream,
                       fm_s, fm_t, lv, tgt, wtab, partials);
    hipLaunchKernelGGL(finalize_kernel, dim3(1), dim3(256), 0, stream,
                       partials, (float*)d_out);
}